// Round 3
// baseline (514.109 us; speedup 1.0000x reference)
//
#include <hip/hip_runtime.h>

// W3J112 constant (3,3,5), already divided by sqrt(5). idx = i*15 + j*5 + k
__constant__ float W3J[45] = {
  0.f, 0.f, -0.18257418583505536f, 0.f, -0.31622776601683794f,
  0.f, 0.31622776601683794f, 0.f, 0.f, 0.f,
  0.31622776601683794f, 0.f, 0.f, 0.f, 0.f,
  0.f, 0.31622776601683794f, 0.f, 0.f, 0.f,
  0.f, 0.f, 0.36514837167011072f, 0.f, 0.f,
  0.f, 0.f, 0.f, 0.31622776601683794f, 0.f,
  0.31622776601683794f, 0.f, 0.f, 0.f, 0.f,
  0.f, 0.f, 0.f, 0.31622776601683794f, 0.f,
  0.f, 0.f, -0.18257418583505536f, 0.f, 0.31622776601683794f
};

__device__ __forceinline__ unsigned short f2bf(float f) {
  unsigned int u = __float_as_uint(f);
  u += 0x7FFFu + ((u >> 16) & 1u);   // round-to-nearest-even
  return (unsigned short)(u >> 16);
}

// Build B in MFMA *fragment-major* bf16 layout, padded to 128x128.
//   M[k][n]: out[z,n] = sum_k geom[z,k] * M[k][n]
//   fragment (t = n>>4, ks = k>>5), lane = ((k>>3)&3)*16 + (n&15), elem j = k&7
//   Bf[((t*4+ks)*64 + lane)*8 + j] = bf16(M[k][n])
// Thread = n (so weight loads along w are stride-1 coalesced), block = k.
__global__ void build_B_kernel(
    const float* __restrict__ field,
    const float* __restrict__ w000, const float* __restrict__ w011,
    const float* __restrict__ w101, const float* __restrict__ w110,
    const float* __restrict__ w112, const float* __restrict__ w202,
    const float* __restrict__ w211, const float* __restrict__ wl0,
    const float* __restrict__ wl1,  const float* __restrict__ wl2,
    unsigned short* __restrict__ Bf)
{
  const float C0  = 0.02795084971874737f;   // sqrt(1/1280)
  const float C1  = 0.051031036307982884f;  // sqrt(3/1152)
  const float C2  = 0.09882117688026186f;   // sqrt(5/512)
  const float IS3 = 0.57735026918962576f;
  const float IS5 = 0.44721359549995794f;

  int k = blockIdx.x;    // input row  0..127
  int n = threadIdx.x;   // output col 0..127
  float val = 0.0f;

  if (n < 120 && k < 120) {
    if (n < 32) {
      int w = n;
      if (k < 32) {                 // g0 -> out0
        int u = k;
        float a = 0.f;
        for (int v = 0; v < 32; ++v) a += w000[u*1024 + v*32 + w] * field[v];
        val = C0 * a + wl0[u*32 + w] * 0.17677669529663689f;
      } else if (k < 80) {          // g1 -> out0 (110)
        int u = (k-32)/3, i = (k-32)%3;
        float a = 0.f;
        for (int v = 0; v < 16; ++v) a += w110[u*512 + v*32 + w] * field[32 + v*3 + i];
        val = C0 * IS3 * a;
      }                             // g2 -> out0 : zero
    } else if (n < 80) {
      int w = (n-32)/3, j = (n-32)%3;
      if (k < 32) {                 // g0 -> out1 (011)
        int u = k;
        float a = 0.f;
        for (int v = 0; v < 16; ++v) a += w011[u*256 + v*16 + w] * field[32 + v*3 + j];
        val = C1 * IS3 * a;
      } else if (k < 80) {          // g1 -> out1 (101 + residual), spatial-diagonal
        int u = (k-32)/3, i = (k-32)%3;
        if (i == j) {
          float a = 0.f;
          for (int v = 0; v < 32; ++v) a += w101[u*512 + v*16 + w] * field[v];
          val = C1 * IS3 * a + wl1[u*16 + w] * 0.25f;
        }
      } else {                      // g2 -> out1 (211 x W3J)
        int u = (k-80)/5, kk = (k-80)%5;
        float c0w = W3J[0*15 + j*5 + kk];
        float c1w = W3J[1*15 + j*5 + kk];
        float c2w = W3J[2*15 + j*5 + kk];
        float a = 0.f;
        for (int v = 0; v < 16; ++v) {
          float s = c0w*field[32+v*3+0] + c1w*field[32+v*3+1] + c2w*field[32+v*3+2];
          a += w211[u*256 + v*16 + w] * s;
        }
        val = C1 * a;
      }
    } else {
      int w = (n-80)/5, k2 = (n-80)%5;
      if (k >= 32 && k < 80) {      // g1 -> out2 (112 x W3J)
        int u = (k-32)/3, i = (k-32)%3;
        float c0w = W3J[i*15 + 0*5 + k2];
        float c1w = W3J[i*15 + 1*5 + k2];
        float c2w = W3J[i*15 + 2*5 + k2];
        float a = 0.f;
        for (int v = 0; v < 16; ++v) {
          float s = c0w*field[32+v*3+0] + c1w*field[32+v*3+1] + c2w*field[32+v*3+2];
          a += w112[u*128 + v*8 + w] * s;
        }
        val = C2 * a;
      } else if (k >= 80) {         // g2 -> out2 (202 + residual), spatial-diagonal
        int u = (k-80)/5, kk = (k-80)%5;
        if (kk == k2) {
          float a = 0.f;
          for (int v = 0; v < 32; ++v) a += w202[u*256 + v*8 + w] * field[v];
          val = C2 * IS5 * a + wl2[u*8 + w] * 0.35355339059327378f;
        }
      }                             // g0 -> out2 : zero
    }
  }
  int t  = n >> 4;
  int ks = k >> 5;
  int lane = ((k >> 3) & 3) * 16 + (n & 15);
  int j  = k & 7;
  Bf[(((t*4 + ks)*64 + lane) << 3) + j] = f2bf(val);
}

typedef __attribute__((ext_vector_type(8))) __bf16 bf16x8;
typedef __attribute__((ext_vector_type(4))) float  f32x4;
typedef __attribute__((ext_vector_type(4))) unsigned int u32x4;

// out(natoms x 120) = geom(natoms x 120) @ M(120x120)
// A fragments loaded straight from global (32 contiguous B per lane),
// B staged once per block into LDS in fragment-major order (conflict-free).
__global__ __launch_bounds__(256, 4) void coupling_main(
    const float* __restrict__ geom, const u32x4* __restrict__ Bfg,
    float* __restrict__ out, int natoms)
{
  __shared__ u32x4 Blds[2048];   // 32 KB, fragment-major: [(t*4+ks)*64 + lane]

  int tid = threadIdx.x;
  // linear copy: consecutive threads -> consecutive 16 B, full LDS BW
  #pragma unroll
  for (int r = 0; r < 8; ++r) {
    int g = tid + r * 256;
    Blds[g] = Bfg[g];
  }
  __syncthreads();

  int lane = tid & 63;
  int wave = tid >> 6;
  int nl   = lane & 15;   // A row (atom within 16-tile) for compute; C col for store
  int kq   = lane >> 4;   // k-quad

  long long base  = (long long)blockIdx.x * 64;
  long long atomA = base + wave * 16 + nl;     // atom whose A row this lane loads
  bool av = atomA < natoms;
  const f32x4* ap = (const f32x4*)(geom + atomA * 120);  // 480 B rows, 16B-aligned

  f32x4 zero = {0.f, 0.f, 0.f, 0.f};
  f32x4 acc[8];
  #pragma unroll
  for (int t = 0; t < 8; ++t) acc[t] = zero;

  #pragma unroll
  for (int ks = 0; ks < 4; ++ks) {
    // A fragment: k = ks*32 + kq*8 .. +7 ; rows have 120 floats, pad k>=120 with 0
    f32x4 fa = zero;
    f32x4 fb = zero;
    if (av && !(ks == 3 && kq == 3)) {
      fa = __builtin_nontemporal_load(&ap[ks * 8 + kq * 2]);
      fb = __builtin_nontemporal_load(&ap[ks * 8 + kq * 2 + 1]);
    }
    u32x4 pk;
    pk.x = ((unsigned)f2bf(fa.y) << 16) | f2bf(fa.x);
    pk.y = ((unsigned)f2bf(fa.w) << 16) | f2bf(fa.z);
    pk.z = ((unsigned)f2bf(fb.y) << 16) | f2bf(fb.x);
    pk.w = ((unsigned)f2bf(fb.w) << 16) | f2bf(fb.z);
    bf16x8 af = __builtin_bit_cast(bf16x8, pk);

    #pragma unroll
    for (int t = 0; t < 8; ++t) {
      bf16x8 bf_ = __builtin_bit_cast(bf16x8, Blds[(t * 4 + ks) * 64 + lane]);
      acc[t] = __builtin_amdgcn_mfma_f32_16x16x32_bf16(af, bf_, acc[t], 0, 0, 0);
    }
  }

  // C/D layout: col = lane&15 (=n within tile), row = kq*4 + reg (=atom within 16)
  long long atom0 = base + wave * 16 + kq * 4;
  #pragma unroll
  for (int t = 0; t < 8; ++t) {
    int n = t * 16 + nl;
    if (n < 120) {
      #pragma unroll
      for (int r2 = 0; r2 < 4; ++r2) {
        long long atom = atom0 + r2;
        if (atom < natoms)
          __builtin_nontemporal_store(acc[t][r2], &out[atom * 120 + n]);
      }
    }
  }
}

extern "C" void kernel_launch(void* const* d_in, const int* in_sizes, int n_in,
                              void* d_out, int out_size, void* d_ws, size_t ws_size,
                              hipStream_t stream) {
  const float* geom  = (const float*)d_in[0];
  const float* field = (const float*)d_in[1];
  const float* w000  = (const float*)d_in[2];
  const float* w011  = (const float*)d_in[3];
  const float* w101  = (const float*)d_in[4];
  const float* w110  = (const float*)d_in[5];
  const float* w112  = (const float*)d_in[6];
  const float* w202  = (const float*)d_in[7];
  const float* w211  = (const float*)d_in[8];
  const float* wl0   = (const float*)d_in[9];
  const float* wl1   = (const float*)d_in[10];
  const float* wl2   = (const float*)d_in[11];
  float* out = (float*)d_out;
  unsigned short* Bf = (unsigned short*)d_ws;   // 128*128 bf16 = 32 KB, fragment-major

  int natoms = in_sizes[0] / 120;

  build_B_kernel<<<dim3(128), dim3(128), 0, stream>>>(
      field, w000, w011, w101, w110, w112, w202, w211, wl0, wl1, wl2, Bf);

  int ntiles = (natoms + 63) / 64;
  coupling_main<<<dim3(ntiles), dim3(256), 0, stream>>>(
      geom, (const u32x4*)Bf, out, natoms);
}